// Round 10
// baseline (321.820 us; speedup 1.0000x reference)
//
#include <hip/hip_runtime.h>
#include <hip/hip_bf16.h>
#include <stdint.h>

typedef __attribute__((ext_vector_type(8))) short s16x8;           // MFMA A/B frag: 8 bf16
typedef __attribute__((ext_vector_type(4))) float f32x4;           // MFMA C/D frag / fp32 vec4
typedef __attribute__((ext_vector_type(8))) unsigned short u16x8;  // 16B vector
typedef __attribute__((ext_vector_type(4))) unsigned short u16x4;  // 8B vector

__device__ __forceinline__ float bf2f(unsigned short u) {
  union { uint32_t u; float f; } v; v.u = ((uint32_t)u) << 16; return v.f;
}
__device__ __forceinline__ unsigned short f2bf(float f) {
  union { float f; uint32_t u; } v; v.f = f;
  uint32_t u = v.u;
  return (unsigned short)((u + 0x7fffu + ((u >> 16) & 1u)) >> 16);  // RNE
}
__device__ __forceinline__ void load_lds16(const void* g, void* l) {
  __builtin_amdgcn_global_load_lds(
      (const __attribute__((address_space(1))) void*)g,
      (__attribute__((address_space(3))) void*)l, 16, 0, 0);
}

template <int N>
__device__ __forceinline__ void vmw() {
  if constexpr (N == 0) asm volatile("s_waitcnt vmcnt(0)" ::: "memory");
  else if constexpr (N == 1) asm volatile("s_waitcnt vmcnt(1)" ::: "memory");
  else if constexpr (N == 2) asm volatile("s_waitcnt vmcnt(2)" ::: "memory");
  else if constexpr (N == 3) asm volatile("s_waitcnt vmcnt(3)" ::: "memory");
  else if constexpr (N == 4) asm volatile("s_waitcnt vmcnt(4)" ::: "memory");
  else asm volatile("s_waitcnt vmcnt(8)" ::: "memory");
}
#define SBAR() asm volatile("s_barrier" ::: "memory")

// PACKED LAYOUT: matrix [R][Kd] -> tiles 64r x 64k. Tile (rt,kt) at ushort
// offset (rt*(Kd/64)+kt)*4096; within tile: plane kb at kb*512, row r at r*8.
// For a 32k step tt, global plane offset = tt*2048 (+ q4*512 within step).
//
// SCHEDULE NOTES:
//  * K1 BM=192 (NPH=2): 2-barrier phase loop validated (91 us); 1-barrier
//    variant = 118 us. K3 (NPH=1): 1-barrier loop.
//  * R10 INSIGHT: A rows are consumed by exactly ONE wave (wV-partitioned);
//    A has ZERO intra-block reuse -> LDS staging of A is a pure double-hop.
//    A fragments are now loaded DIRECTLY global->VGPR with a one-tile-ahead
//    named double-buffer (aA/aB, unroll-by-2 -> all indices compile-time).
//    Only B (x8-16 reuse across waves) stays LDS-staged. Uniform vmcnt.
//  * R7 BUG (fixed): A2 offset applied exactly once, in-kernel (1024+...).
// ---------------------------------------------------------------------------
// P0: merged prep. blocks [0,3072): transpose x -> Xtp packed.
//     blocks [3072,5376): pack A -> Abp. block 5376: cvt W/b -> Wb.
// ---------------------------------------------------------------------------
__global__ __launch_bounds__(256) void k_prep(const void* __restrict__ xin,
                                              const void* __restrict__ Ain,
                                              const void* __restrict__ W0,
                                              const void* __restrict__ b0,
                                              const void* __restrict__ W1,
                                              const void* __restrict__ b1,
                                              unsigned short* __restrict__ xtp,
                                              unsigned short* __restrict__ Abp,
                                              unsigned short* __restrict__ wb) {
  __shared__ __align__(16) unsigned short sh[64 * 65];  // 4160: fits both tiles
  const int t = threadIdx.x;
  const int bid = blockIdx.x;
  int fp;
  {
    uint32_t u = ((const uint32_t*)xin)[(t & 63) * 97 + 1];
    int e = (u >> 7) & 0xFF;
    unsigned long long m = __ballot(e > 150);
    fp = (__popcll(m) > 6) ? 1 : 0;
  }

  if (bid < 3072) {
    // ---- transpose: x (3072 w x 4096 m) -> Xtp packed (rows m, k=w) ----
    const int w0 = (bid % 48) * 64;
    const int m0 = (bid / 48) * 64;
    if (fp) {
      const float* xf = (const float*)xin;
#pragma unroll
      for (int rep = 0; rep < 4; ++rep) {
        int vi = t + rep * 256;
        int r = vi >> 4;                // w-local
        int c4 = (vi & 15) * 4;        // m-local
        f32x4 v = *(const f32x4*)(xf + (uint64_t)(w0 + r) * 4096 + m0 + c4);
#pragma unroll
        for (int u = 0; u < 4; ++u) sh[(c4 + u) * 65 + r] = f2bf(v[u]);
      }
    } else {
      const unsigned short* xb = (const unsigned short*)xin;
#pragma unroll
      for (int rep = 0; rep < 2; ++rep) {
        int vi = t + rep * 256;
        int r = vi >> 3;
        int c8 = (vi & 7) * 8;
        u16x8 v = *(const u16x8*)(xb + (uint64_t)(w0 + r) * 4096 + m0 + c8);
#pragma unroll
        for (int u = 0; u < 8; ++u) sh[(c8 + u) * 65 + r] = v[u];
      }
    }
    __syncthreads();
    unsigned short* dst = xtp + ((uint64_t)(m0 >> 6) * 48 + (w0 >> 6)) * 4096;
#pragma unroll
    for (int rep = 0; rep < 2; ++rep) {
      int vi = t + rep * 256;           // [0,512)
      int kb = vi >> 6, r = vi & 63;
      u16x8 v;
#pragma unroll
      for (int u = 0; u < 8; ++u) v[u] = sh[r * 65 + kb * 8 + u];
      *(u16x8*)(dst + kb * 512 + r * 8) = v;
    }
  } else if (bid < 5376) {
    // ---- pack A (3072x3072) -> Abp; LDS bounce planes padded to 520 ----
    const int b2 = bid - 3072;
    const int kt = b2 % 48, rt = b2 / 48;
    if (fp) {
      const float* Af = (const float*)Ain;
#pragma unroll
      for (int rep = 0; rep < 4; ++rep) {
        int vi = t + rep * 256;
        int r = vi >> 4;
        int c4 = (vi & 15) * 4;
        f32x4 v = *(const f32x4*)(Af + (uint64_t)(rt * 64 + r) * 3072 + kt * 64 + c4);
        int kb = c4 >> 3, e = c4 & 7;
#pragma unroll
        for (int u = 0; u < 4; ++u) sh[kb * 520 + r * 8 + e + u] = f2bf(v[u]);
      }
    } else {
      const unsigned short* Ab16 = (const unsigned short*)Ain;
#pragma unroll
      for (int rep = 0; rep < 2; ++rep) {
        int vi = t + rep * 256;
        int r = vi >> 3;
        int c8 = (vi & 7) * 8;
        u16x8 v = *(const u16x8*)(Ab16 + (uint64_t)(rt * 64 + r) * 3072 + kt * 64 + c8);
#pragma unroll
        for (int u = 0; u < 8; ++u) sh[(c8 >> 3) * 520 + r * 8 + u] = v[u];
      }
    }
    __syncthreads();
    unsigned short* dst = Abp + ((uint64_t)rt * 48 + kt) * 4096;
#pragma unroll
    for (int rep = 0; rep < 2; ++rep) {
      int vi = t + rep * 256;
      int kb = vi >> 6, r = vi & 63;
      u16x8 v;
#pragma unroll
      for (int u = 0; u < 8; ++u) v[u] = sh[kb * 520 + r * 8 + u];
      *(u16x8*)(dst + kb * 512 + r * 8) = v;
    }
  } else {
    // ---- W0,b0,W1,b1 -> contiguous bf16 block wb[16640] ----
    for (int i = t; i < 16640; i += 256) {
      const void* src; int off;
      if (i < 8192)        { src = W0; off = i; }
      else if (i < 8320)   { src = b0; off = i - 8192; }
      else if (i < 16512)  { src = W1; off = i - 8320; }
      else                 { src = b1; off = i - 16512; }
      wb[i] = fp ? f2bf(((const float*)src)[off]) : ((const unsigned short*)src)[off];
    }
  }
}

// ---------------------------------------------------------------------------
// K1: fused NT GEMM + conv + GLU -> packed H1. BM=192x256, 2-phase loop,
// counted vmcnt, 4-deep B-only LDS ring (16 planes/slot), A direct-to-reg
// with one-tile-ahead double buffer. 256 blocks = 1/CU.
// ---------------------------------------------------------------------------
__global__ __launch_bounds__(512, 2) void k1_gemm_glu(
    const unsigned short* __restrict__ Am,
    const unsigned short* __restrict__ Bm,
    const unsigned short* __restrict__ W,
    const unsigned short* __restrict__ bias,
    unsigned short* __restrict__ H) {
  constexpr int IF  = 6;
  constexpr int BUFS = 16 * 512;           // 16 B planes per 32k slot
  constexpr int NT  = 96;
  constexpr int Kt  = 48;
  constexpr int NRB = 12;
  constexpr int SME = 192 * 264;           // 50688 > 4*BUFS (32768)

  __shared__ __align__(16) unsigned short smem[SME];

  const int t    = threadIdx.x;
  const int lane = t & 63;
  const int wid  = t >> 6;
  const int wV   = wid >> 2;
  const int wM   = wid & 3;
  const int fr   = lane & 15;
  const int q4   = lane >> 4;
  const int v0   = blockIdx.x * 192;
  const int m0   = blockIdx.y * 256;
  const int brt0 = m0 >> 6;

  // B staging: 2 planes/wave (16 planes / 8 waves), uniform
  const unsigned short* srcb[2];
  int ldso[2];
#pragma unroll
  for (int q = 0; q < 2; ++q) {
    const int pi = wid + 8 * q;
    srcb[q] = Bm + ((uint64_t)(brt0 + (pi >> 2)) * Kt) * 4096 + (pi & 3) * 512 +
              lane * 8;
    ldso[q] = pi * 512;
  }

  // A direct-load per-lane offsets (packed layout), per fragment
  uint64_t aog[IF];
#pragma unroll
  for (int i = 0; i < IF; ++i) {
    const int g = v0 + wV * 96 + i * 16 + fr;
    aog[i] = ((uint64_t)(g >> 6) * Kt) * 4096 + q4 * 512 + (uint64_t)(g & 63) * 8;
  }

  int boff[4];
#pragma unroll
  for (int j = 0; j < 4; ++j)
    boff[j] = (wM * 4 + q4) * 512 + (j * 16 + fr) * 8;

  f32x4 acc[IF][4] = {};
  s16x8 aA[IF], aB[IF];

  // ---- prologue: A(0) to regs first, then B stages 0..2 ----
#pragma unroll
  for (int i = 0; i < IF; ++i) aA[i] = *(const s16x8*)(Am + aog[i]);
#pragma unroll
  for (int pt = 0; pt < 3; ++pt)
#pragma unroll
    for (int q = 0; q < 2; ++q)
      load_lds16(srcb[q] + pt * 2048, smem + pt * BUFS + ldso[q]);
  vmw<4>();  // A(0) + stage(0) done; stage(1,2) in flight
  SBAR();

  // ---- main loop: unroll-by-2 so aA/aB alternation is compile-time ----
  auto tile = [&](int tt, s16x8 (&CUR)[IF], s16x8 (&NXT)[IF]) {
    const unsigned short* buf = smem + (tt & 3) * BUFS;
    s16x8 bfr[4];
    // phase 0: issue A(tt+1), read B frags, stage half of tt+3
    if (tt + 1 < NT) {
#pragma unroll
      for (int i = 0; i < IF; ++i)
        NXT[i] = *(const s16x8*)(Am + aog[i] + (uint64_t)(tt + 1) * 2048);
    }
#pragma unroll
    for (int j = 0; j < 4; ++j) bfr[j] = *(const s16x8*)(buf + boff[j]);
    if (tt + 3 < NT)
      load_lds16(srcb[0] + (uint64_t)(tt + 3) * 2048,
                 smem + ((tt + 3) & 3) * BUFS + ldso[0]);
    SBAR();
    __builtin_amdgcn_s_setprio(1);
#pragma unroll
    for (int ii = 0; ii < 3; ++ii)
#pragma unroll
      for (int j = 0; j < 4; ++j)
        acc[ii][j] = __builtin_amdgcn_mfma_f32_16x16x32_bf16(CUR[ii], bfr[j],
                                                             acc[ii][j], 0, 0, 0);
    __builtin_amdgcn_s_setprio(0);
    SBAR();
    // phase 1: stage other half of tt+3, MFMA remaining frags
    if (tt + 3 < NT)
      load_lds16(srcb[1] + (uint64_t)(tt + 3) * 2048,
                 smem + ((tt + 3) & 3) * BUFS + ldso[1]);
    SBAR();
    __builtin_amdgcn_s_setprio(1);
#pragma unroll
    for (int ii = 3; ii < 6; ++ii)
#pragma unroll
      for (int j = 0; j < 4; ++j)
        acc[ii][j] = __builtin_amdgcn_mfma_f32_16x16x32_bf16(CUR[ii], bfr[j],
                                                             acc[ii][j], 0, 0, 0);
    __builtin_amdgcn_s_setprio(0);
    if (tt + 3 < NT) { vmw<2>(); } else { vmw<0>(); }
    SBAR();
  };
  for (int tt = 0; tt < NT; tt += 2) {
    tile(tt, aA, aB);
    tile(tt + 1, aB, aA);
  }

  // ---- epilogue: G-tile -> LDS (stride 264), conv + GLU, packed H ----
  __syncthreads();
  {
    const int rr = q4 * 4;
#pragma unroll
    for (int i = 0; i < IF; ++i)
#pragma unroll
      for (int j = 0; j < 4; ++j) {
        const int col = wM * 64 + j * 16 + fr;
#pragma unroll
        for (int r = 0; r < 4; ++r) {
          const int row = wV * 96 + i * 16 + rr + r;
          smem[row * 264 + col] = f2bf(acc[i][j][r]);
        }
      }
  }
  __syncthreads();

  s16x8 wf[2][8];
#pragma unroll
  for (int ksi = 0; ksi < 2; ++ksi)
#pragma unroll
    for (int j = 0; j < 8; ++j)
      wf[ksi][j] = *(const s16x8*)(W + (j * 16 + fr) * 64 + ksi * 32 + q4 * 8);
  float bj[8];
#pragma unroll
  for (int j = 0; j < 8; ++j) bj[j] = bf2f(bias[j * 16 + fr]);

#pragma unroll
  for (int rep = 0; rep < 2; ++rep) {
    const int rb = rep * 8 + wid;
    if (rb < NRB) {
#pragma unroll
      for (int bb = 0; bb < 4; ++bb) {
        f32x4 acc2[8] = {};
#pragma unroll
        for (int ksi = 0; ksi < 2; ++ksi) {
          s16x8 af = *(const s16x8*)(smem + (rb * 16 + fr) * 264 + bb * 64 +
                                     ksi * 32 + q4 * 8);
#pragma unroll
          for (int j = 0; j < 8; ++j)
            acc2[j] = __builtin_amdgcn_mfma_f32_16x16x32_bf16(af, wf[ksi][j],
                                                              acc2[j], 0, 0, 0);
        }
        const int v = v0 + rb * 16 + q4 * 4;
#pragma unroll
        for (int j = 0; j < 4; ++j) {
          u16x4 pk;
#pragma unroll
          for (int r = 0; r < 4; ++r) {
            float lhs = acc2[j][r] + bj[j];
            float rhs = acc2[j + 4][r] + bj[j + 4];
            float sg = 1.0f / (1.0f + __expf(-rhs));
            pk[r] = f2bf(lhs * sg);
          }
          const int o = j * 16 + fr;
          const int hrow = m0 + bb * 64 + o;
          *(u16x4*)(H + ((uint64_t)(hrow >> 6) * 48 + (v >> 6)) * 4096 +
                    ((v >> 3) & 7) * 512 + (hrow & 63) * 8 + (v & 7)) = pk;
        }
      }
    }
  }
}

// ---------------------------------------------------------------------------
// K3: fused NT GEMM + conv + GLU + max-with-H1 -> fp32 out. 128x128 tiles
// (grid 8x32 = 256 blocks), 1-barrier loop, counted vmcnt, 4-deep B-only
// ring (8 planes/slot, 16 KB), A direct-to-reg double buffer. A2 offset
// (rows 1024+) applied once, in aog. LDS = 35 KB.
// ---------------------------------------------------------------------------
__global__ __launch_bounds__(512, 2) void k3_gemm_glu(
    const unsigned short* __restrict__ Am,
    const unsigned short* __restrict__ Bm,
    const unsigned short* __restrict__ W,
    const unsigned short* __restrict__ bias,
    const unsigned short* __restrict__ Hprev,
    float* __restrict__ outp) {
  constexpr int IF  = 2;
  constexpr int BUFS = 8 * 512;            // 8 B planes per 32k slot
  constexpr int NT  = 96;
  constexpr int Kt  = 48;
  constexpr int SME = 128 * 136;           // 17408 > 4*BUFS (16384)

  __shared__ __align__(16) unsigned short smem[SME];

  const int t    = threadIdx.x;
  const int lane = t & 63;
  const int wid  = t >> 6;
  const int wV   = wid >> 1;   // 0..3 : 32-row v-quarter
  const int wM   = wid & 1;    // 0..1 : 64-wide m-slice
  const int fr   = lane & 15;
  const int q4   = lane >> 4;
  const int v0   = blockIdx.x * 128;
  const int m0   = blockIdx.y * 128;
  const int brt0 = m0 >> 6;

  // B staging: 1 plane/wave (8 planes / 8 waves)
  const unsigned short* srcb0 =
      Bm + ((uint64_t)(brt0 + (wid >> 2)) * Kt) * 4096 + (wid & 3) * 512 +
      lane * 8;
  const int ldso0 = wid * 512;

  // A direct offsets; A2 rows = 1024 + v (SOLE offset application)
  uint64_t aog[IF];
#pragma unroll
  for (int i = 0; i < IF; ++i) {
    const int g = 1024 + v0 + wV * 32 + i * 16 + fr;
    aog[i] = ((uint64_t)(g >> 6) * Kt) * 4096 + q4 * 512 + (uint64_t)(g & 63) * 8;
  }

  int boff[4];
#pragma unroll
  for (int j = 0; j < 4; ++j)
    boff[j] = (wM * 4 + q4) * 512 + (j * 16 + fr) * 8;

  f32x4 acc[IF][4] = {};
  s16x8 aA[IF], aB[IF];

  // ---- prologue: A(0) first, then B stages 0..2 ----
#pragma unroll
  for (int i = 0; i < IF; ++i) aA[i] = *(const s16x8*)(Am + aog[i]);
#pragma unroll
  for (int pt = 0; pt < 3; ++pt)
    load_lds16(srcb0 + pt * 2048, smem + pt * BUFS + ldso0);
  vmw<2>();  // A(0) + stage(0) done; stage(1,2) in flight
  SBAR();

  auto tile = [&](int tt, s16x8 (&CUR)[IF], s16x8 (&NXT)[IF]) {
    const unsigned short* buf = smem + (tt & 3) * BUFS;
    s16x8 bfr[4];
    if (tt + 1 < NT) {
#pragma unroll
      for (int i = 0; i < IF; ++i)
        NXT[i] = *(const s16x8*)(Am + aog[i] + (uint64_t)(tt + 1) * 2048);
    }
#pragma unroll
    for (int j = 0; j < 4; ++j) bfr[j] = *(const s16x8*)(buf + boff[j]);
    if (tt + 3 < NT)
      load_lds16(srcb0 + (uint64_t)(tt + 3) * 2048,
                 smem + ((tt + 3) & 3) * BUFS + ldso0);
    __builtin_amdgcn_s_setprio(1);
#pragma unroll
    for (int i = 0; i < IF; ++i)
#pragma unroll
      for (int j = 0; j < 4; ++j)
        acc[i][j] = __builtin_amdgcn_mfma_f32_16x16x32_bf16(CUR[i], bfr[j],
                                                            acc[i][j], 0, 0, 0);
    __builtin_amdgcn_s_setprio(0);
    if (tt + 3 < NT) { vmw<1>(); } else { vmw<0>(); }
    SBAR();
  };
  for (int tt = 0; tt < NT; tt += 2) {
    tile(tt, aA, aB);
    tile(tt + 1, aB, aA);
  }

  // ---- epilogue: G-tile [128][128] -> LDS stride 136, conv+GLU+max ----
  __syncthreads();
  {
    const int rr = q4 * 4;
#pragma unroll
    for (int i = 0; i < IF; ++i)
#pragma unroll
      for (int j = 0; j < 4; ++j) {
        const int col = wM * 64 + j * 16 + fr;
#pragma unroll
        for (int r = 0; r < 4; ++r) {
          const int row = wV * 32 + i * 16 + rr + r;
          smem[row * 136 + col] = f2bf(acc[i][j][r]);
        }
      }
  }
  __syncthreads();

  s16x8 wf[2][8];
#pragma unroll
  for (int ksi = 0; ksi < 2; ++ksi)
#pragma unroll
    for (int j = 0; j < 8; ++j)
      wf[ksi][j] = *(const s16x8*)(W + (j * 16 + fr) * 64 + ksi * 32 + q4 * 8);
  float bj[8];
#pragma unroll
  for (int j = 0; j < 8; ++j) bj[j] = bf2f(bias[j * 16 + fr]);

  {
    const int rb = wid;              // 8 row-blocks of 16 v-rows
#pragma unroll
    for (int bb = 0; bb < 2; ++bb) {
      f32x4 acc2[8] = {};
#pragma unroll
      for (int ksi = 0; ksi < 2; ++ksi) {
        s16x8 af = *(const s16x8*)(smem + (rb * 16 + fr) * 136 + bb * 64 +
                                   ksi * 32 + q4 * 8);
#pragma unroll
        for (int j = 0; j < 8; ++j)
          acc2[j] = __builtin_amdgcn_mfma_f32_16x16x32_bf16(af, wf[ksi][j],
                                                            acc2[j], 0, 0, 0);
      }
      const int v = v0 + rb * 16 + q4 * 4;
#pragma unroll
      for (int j = 0; j < 4; ++j) {
        const int o = j * 16 + fr;
        const int hrow = m0 + bb * 64 + o;
        const int c = 1024 + v;  // H1 col; Kt of H1 is 48
        u16x4 hv = *(const u16x4*)(Hprev +
            ((uint64_t)(hrow >> 6) * 48 + (c >> 6)) * 4096 +
            ((c >> 3) & 7) * 512 + (hrow & 63) * 8 + (c & 7));
        float* op = outp + (uint64_t)v * 4096 + hrow;
#pragma unroll
        for (int r = 0; r < 4; ++r) {
          float lhs = acc2[j][r] + bj[j];
          float rhs = acc2[j + 4][r] + bj[j + 4];
          float sg = 1.0f / (1.0f + __expf(-rhs));
          op[(uint64_t)r * 4096] = fmaxf(lhs * sg, bf2f(hv[r]));
        }
      }
    }
  }
}

// ---------------------------------------------------------------------------
extern "C" void kernel_launch(void* const* d_in, const int* in_sizes, int n_in,
                              void* d_out, int out_size, void* d_ws, size_t ws_size,
                              hipStream_t stream) {
  (void)in_sizes; (void)n_in; (void)out_size; (void)ws_size;
  const void* x  = d_in[0];  // [3072][64][64]
  const void* A  = d_in[1];  // [3072][3072]
  const void* W0 = d_in[2];  // [128][64]
  const void* b0 = d_in[3];  // [128]
  const void* W1 = d_in[4];  // [128][64]
  const void* b1 = d_in[5];  // [128]
  float* out = (float*)d_out;  // [1024][64][64] fp32

  char* ws = (char*)d_ws;
  unsigned short* Xtp = (unsigned short*)(ws + 0);         // 25165824 B
  unsigned short* Abp = (unsigned short*)(ws + 25165824);  // 18874368 B
  unsigned short* Wb  = (unsigned short*)(ws + 44040192);  // 33280 B
  unsigned short* H1p = (unsigned short*)(ws + 44105728);  // 25165824 B -> end 69271552

  // P0: transpose (3072 blocks) + packA (2304) + cvtW (1)
  k_prep<<<5377, 256, 0, stream>>>(x, A, W0, b0, W1, b1, Xtp, Abp, Wb);
  // K1: H1 = GLU(W0.(A.Xt^T)+b0), 192x256 tiles -> 256 blocks = 1/CU.
  k1_gemm_glu<<<dim3(16, 16), 512, 0, stream>>>(Abp, Xtp, Wb, Wb + 8192, H1p);
  // K3: out = max(H1 mid, GLU(W1.(A2.H1^T)+b1)), 128x128 tiles -> 8x32 =
  // 256 blocks. Plain Abp (A2 offset inside, in aog).
  k3_gemm_glu<<<dim3(8, 32), 512, 0, stream>>>(
      Abp, H1p, Wb + 8320, Wb + 16512, H1p, out);
}